// Round 17
// baseline (923.509 us; speedup 1.0000x reference)
//
#include <hip/hip_runtime.h>

// ---------- types ----------
typedef __bf16 bf16;
typedef __attribute__((ext_vector_type(8))) __bf16 bf16x8;
typedef __attribute__((ext_vector_type(4))) float f32x4;
typedef __attribute__((ext_vector_type(2))) _Float16 h16x2;

#define T_SEQ 1024
#define D_MODEL 512
#define N_INT 2048
#define NHEADS 8
#define IN_DIM 372
#define IN_PAD 384
#define OUT_DIM 186
#define OUT_PAD 256

__device__ inline void gld16(const bf16* g, bf16* l) {
  __builtin_amdgcn_global_load_lds((const __attribute__((address_space(1))) void*)g,
                                   (__attribute__((address_space(3))) void*)l, 16, 0, 0);
}

// block-wide sum of two values (256 threads)
__device__ inline void block_sum2(float& a, float& b, float* red) {
#pragma unroll
  for (int o = 32; o > 0; o >>= 1) {
    a += __shfl_down(a, o, 64);
    b += __shfl_down(b, o, 64);
  }
  __syncthreads();
  if ((threadIdx.x & 63) == 0) {
    int w = threadIdx.x >> 6;
    red[2 * w] = a;
    red[2 * w + 1] = b;
  }
  __syncthreads();
  a = red[0] + red[2] + red[4] + red[6];
  b = red[1] + red[3] + red[5] + red[7];
}

// ---------- transpose + fp32->bf16 convert ----------
__global__ __launch_bounds__(256) void transpose_cvt(const float* __restrict__ in,
                                                     bf16* __restrict__ out,
                                                     int rows, int cols) {
  __shared__ float tile[32][33];
  size_t zoff = (size_t)blockIdx.z * rows * cols;
  in += zoff;
  out += zoff;
  int c0 = blockIdx.x * 32, r0 = blockIdx.y * 32;
#pragma unroll
  for (int i = threadIdx.y; i < 32; i += 8)
    tile[i][threadIdx.x] = in[(size_t)(r0 + i) * cols + c0 + threadIdx.x];
  __syncthreads();
#pragma unroll
  for (int i = threadIdx.y; i < 32; i += 8)
    out[(size_t)(c0 + i) * rows + r0 + threadIdx.x] = (bf16)tile[threadIdx.x][i];
}

// ---------- zero-padded transpose + cvt ----------
__global__ __launch_bounds__(256) void pad_trans(const float* __restrict__ in,
                                                 bf16* __restrict__ out,
                                                 int R, int C, int outLd) {
  __shared__ float tile[32][33];
  int c0 = blockIdx.x * 32, r0 = blockIdx.y * 32;
#pragma unroll
  for (int i = threadIdx.y; i < 32; i += 8) {
    int r = r0 + i, c = c0 + threadIdx.x;
    tile[i][threadIdx.x] = (r < R && c < C) ? in[(size_t)r * C + c] : 0.f;
  }
  __syncthreads();
#pragma unroll
  for (int i = threadIdx.y; i < 32; i += 8)
    out[(size_t)(c0 + i) * outLd + r0 + threadIdx.x] = (bf16)tile[threadIdx.x][i];
}

// ---------- x fp32 [2048][372] -> xbf bf16 [2048][384] zero-padded ----------
__global__ __launch_bounds__(256) void cvt_pad_x(const float* __restrict__ x,
                                                 bf16* __restrict__ xbf) {
  size_t r = blockIdx.x;
  for (int c = threadIdx.x; c < IN_PAD; c += 256)
    xbf[r * IN_PAD + c] = (c < IN_DIM) ? (bf16)x[r * IN_DIM + c] : (bf16)0.f;
}

// ---------- RoPE table: packed fp16 (cos,sin) per (t,i) ----------
__global__ __launch_bounds__(256) void rope_tables(h16x2* __restrict__ cs) {
  int t = blockIdx.x;
  for (int i = threadIdx.x; i < 1024; i += 256) {
    float ph = (float)t * exp2f(-16.0f * (float)i * (1.0f / 1024.0f));
    h16x2 v;
    v[0] = (_Float16)cosf(ph);
    v[1] = (_Float16)sinf(ph);
    cs[(size_t)t * 1024 + i] = v;
  }
}

// ---------- ln0: h = LN(z) ----------
__global__ __launch_bounds__(256) void ln0(const float* __restrict__ zin,
                                           float* __restrict__ h, bf16* __restrict__ hbf,
                                           bf16* __restrict__ hT) {
  __shared__ float red[8];
  size_t r = blockIdx.x;
  int tid = threadIdx.x;
  float v0 = zin[r * 512 + tid], v1 = zin[r * 512 + tid + 256];
  float s = v0 + v1, s2 = v0 * v0 + v1 * v1;
  block_sum2(s, s2, red);
  float mean = s * (1.f / 512.f);
  float var = s2 * (1.f / 512.f) - mean * mean;
  float rs = rsqrtf(var + 1e-5f);
  float o0 = (v0 - mean) * rs, o1 = (v1 - mean) * rs;
  h[r * 512 + tid] = o0;
  h[r * 512 + tid + 256] = o1;
  hbf[r * 512 + tid] = (bf16)o0;
  hbf[r * 512 + tid + 256] = (bf16)o1;
  int b = (int)(r >> 10), t = (int)(r & (T_SEQ - 1));
  hT[((size_t)b * 512 + tid) * T_SEQ + t] = (bf16)o0;
  hT[((size_t)b * 512 + tid + 256) * T_SEQ + t] = (bf16)o1;
}

// ---------- wave-per-row in-place LN on bf16 rows of 512 (4 rows/block) ----------
__global__ __launch_bounds__(256) void ln_rows(bf16* __restrict__ io) {
  const int wid = threadIdx.x >> 6, lane = threadIdx.x & 63;
  size_t r = (size_t)blockIdx.x * 4 + wid;
  bf16* p = io + r * 512 + lane * 8;
  bf16x8 v = *(const bf16x8*)p;
  float f[8], s = 0.f, s2 = 0.f;
#pragma unroll
  for (int j = 0; j < 8; ++j) {
    f[j] = (float)v[j];
    s += f[j];
    s2 += f[j] * f[j];
  }
#pragma unroll
  for (int o = 32; o > 0; o >>= 1) {
    s += __shfl_xor(s, o, 64);
    s2 += __shfl_xor(s2, o, 64);
  }
  float mean = s * (1.f / 512.f);
  float var = s2 * (1.f / 512.f) - mean * mean;
  float rs = rsqrtf(var + 1e-5f);
  bf16x8 o;
#pragma unroll
  for (int j = 0; j < 8; ++j) o[j] = (bf16)((f[j] - mean) * rs);
  *(bf16x8*)p = o;
}

// ---------- fused: z=sum(8 partials of batch b); h=LN(h_res+LN(z)) ----------
__global__ __launch_bounds__(256) void psum_lnd(const bf16* __restrict__ part,
                                                float* __restrict__ h, bf16* __restrict__ hbf,
                                                bf16* __restrict__ hT) {
  __shared__ float red[8];
  int b = blockIdx.x >> 10;
  int r = blockIdx.x & 1023;
  int tid = threadIdx.x;
  float z0 = 0.f, z1 = 0.f;
#pragma unroll
  for (int k = 0; k < 8; ++k) {
    size_t off = ((size_t)(b * 8 + k) << 19) + (size_t)r * 512;
    z0 += (float)part[off + tid];
    z1 += (float)part[off + tid + 256];
  }
  float s = z0 + z1, s2 = z0 * z0 + z1 * z1;
  block_sum2(s, s2, red);
  float m1 = s * (1.f / 512.f);
  float v1_ = s2 * (1.f / 512.f) - m1 * m1;
  float rs1 = rsqrtf(v1_ + 1e-5f);
  size_t R = (size_t)b * T_SEQ + r;
  float a0 = (z0 - m1) * rs1 + h[R * 512 + tid];
  float a1 = (z1 - m1) * rs1 + h[R * 512 + tid + 256];
  s = a0 + a1;
  s2 = a0 * a0 + a1 * a1;
  block_sum2(s, s2, red);
  float m2 = s * (1.f / 512.f);
  float v2_ = s2 * (1.f / 512.f) - m2 * m2;
  float rs2 = rsqrtf(v2_ + 1e-5f);
  float o0 = (a0 - m2) * rs2, o1 = (a1 - m2) * rs2;
  h[R * 512 + tid] = o0;
  h[R * 512 + tid + 256] = o1;
  hbf[R * 512 + tid] = (bf16)o0;
  hbf[R * 512 + tid + 256] = (bf16)o1;
  hT[((size_t)b * 512 + tid) * T_SEQ + r] = (bf16)o0;
  hT[((size_t)b * 512 + tid + 256) * T_SEQ + r] = (bf16)o1;
}

// ==================================================================
// 128(M) x TN(N) MFMA GEMM, batch-merged (zz = id&15 = b*8+h).
// PIPE=1: r9-proven single-barrier 2-phase loop (drain-0).
// PIPE=2: 3-buffer depth-2 prefetch with COUNTED vmcnt (T4) + single barrier.
//   iter t: {stage(t+2)} -> {compute(t)} -> {vmcnt(L)+barrier}, L = loads/stage
//   (waits only tile t+1's loads, issued a full iteration earlier).
// LDS-staged coalesced epilogue. XOR-swizzle (T2). XCD pin (T1).
// ==================================================================
template <int MODE, int TN, int PIPE>
__device__ __forceinline__ void gemm_body(const bf16* __restrict__ Abase,
                                          const bf16* __restrict__ Bbase,
                                          const bf16* __restrict__ aux,
                                          const float* __restrict__ fbias,
                                          float* __restrict__ fout,
                                          bf16* __restrict__ bout) {
  const int id = blockIdx.x;
  int zz = 0, r_, cb = 0;
  if constexpr (MODE >= 5) {
    r_ = id;
  } else if constexpr (MODE == 4) {
    cb = id & 15;   // b*8+chunk; chunk pinned to XCD chunk%8 (shared decT chunk L2-local)
    r_ = id >> 4;   // 0..31 = bi(8) x bj(4)
  } else {
    zz = id & 15;   // b*8+h  (head pinned to XCD h%8)
    r_ = id >> 4;
  }
  int bi, bj;
  if constexpr (MODE == 1) {
    int l = r_;  // l = bi*(bi+1)+bj, 72 tiles
    bi = (int)sqrtf((float)l);
    while ((bi + 1) * (bi + 2) <= l) ++bi;
    while (bi * (bi + 1) > l) --bi;
    bj = l - bi * (bi + 1);
  } else if constexpr (MODE >= 5) {
    bi = r_ & 15;
    bj = r_ >> 4;
  } else {
    bi = r_ & 7;
    bj = r_ >> 3;
  }

  const bf16* A;
  const bf16* Bt;
  int lda, ldb, kend;
  if constexpr (MODE == 1) {
    A = Abase + ((size_t)zz << 21); lda = N_INT;  // qr[b][h][1024][2048]
    Bt = A; ldb = N_INT;
    kend = N_INT;
  } else if constexpr (MODE == 2) {
    A = Abase + ((size_t)zz << 20); lda = T_SEQ;  // S[b][h][1024][1024]
    Bt = Bbase + (size_t)(zz >> 3) * 512 * T_SEQ; ldb = T_SEQ;
    kend = (bi + 1) * 128;
  } else if constexpr (MODE == 3) {
    A = Abase + ((size_t)zz << 19); lda = 512;    // ykv[b][h][1024][512]
    Bt = Bbase + (size_t)(zz & 7) * N_INT * 512; ldb = 512;
    kend = 512;
  } else if constexpr (MODE == 4) {
    A = Abase + ((size_t)(cb >> 3) << 24) + (size_t)(cb & 7) * 2048; lda = 16384;
    Bt = Bbase + (size_t)(cb & 7) * 2048; ldb = 16384;
    kend = 2048;
  } else if constexpr (MODE == 5) {
    A = Abase; lda = IN_PAD;
    Bt = Bbase; ldb = IN_PAD;
    kend = IN_PAD;
  } else {
    A = Abase; lda = 512;
    Bt = Bbase; ldb = 512;
    kend = 512;
  }

  const int tid = threadIdx.x;
  const int trow = tid >> 3, tq = tid & 7;
  const int sq = tq ^ (trow & 7);
  const bf16* ags = A + (size_t)(bi * 128 + trow) * lda + sq * 8;
  const bf16* bgs = Bt + (size_t)(bj * TN + trow) * ldb + sq * 8;

  constexpr int NBUF = PIPE + 1;
  __shared__ __align__(16) bf16 As[NBUF][128 * 64];
  __shared__ __align__(16) bf16 Bs[NBUF][TN * 64];
  const int so = tid * 8;

  const int lane = tid & 63, wid = tid >> 6;
  const int wr = wid >> 1, wc = wid & 1;
  const int fr = lane & 15, fg = lane >> 4;
  const int axor = fr & 7;
  constexpr int NR = TN / 32;

  f32x4 acc[4][NR] = {};

  auto stage = [&](int buf, int kk) {
#pragma unroll
    for (int p = 0; p < 4; ++p)
      gld16(ags + (size_t)(p * 32) * lda + kk, &As[buf][p * 2048 + so]);
#pragma unroll
    for (int p = 0; p < TN / 32; ++p)
      gld16(bgs + (size_t)(p * 32) * ldb + kk, &Bs[buf][p * 2048 + so]);
  };

  auto compute = [&](int cur) {
    __builtin_amdgcn_s_setprio(1);
#pragma unroll
    for (int s = 0; s < 2; ++s) {
      bf16x8 af[4], bfv[NR];
#pragma unroll
      for (int m = 0; m < 4; ++m)
        af[m] = *(const bf16x8*)(&As[cur][(wr * 64 + m * 16 + fr) * 64 + (((s * 4 + fg) ^ axor) * 8)]);
#pragma unroll
      for (int n = 0; n < NR; ++n)
        bfv[n] = *(const bf16x8*)(&Bs[cur][(wc * (TN / 2) + n * 16 + fr) * 64 + (((s * 4 + fg) ^ axor) * 8)]);
#pragma unroll
      for (int m = 0; m < 4; ++m)
#pragma unroll
        for (int n = 0; n < NR; ++n)
          acc[m][n] = __builtin_amdgcn_mfma_f32_16x16x32_bf16(af[m], bfv[n], acc[m][n], 0, 0, 0);
    }
    __builtin_amdgcn_s_setprio(0);
  };

  const int nt = kend >> 6;
  if constexpr (PIPE == 1) {
    stage(0, 0);
    asm volatile("s_waitcnt vmcnt(0)" ::: "memory");
    __builtin_amdgcn_s_barrier();
    for (int t = 0; t < nt; ++t) {
      const int cur = t & 1;
      if (t + 1 < nt) stage(cur ^ 1, (t + 1) << 6);
      compute(cur);
      asm volatile("s_waitcnt vmcnt(0)" ::: "memory");
      __builtin_amdgcn_sched_barrier(0);
      __builtin_amdgcn_s_barrier();
      __builtin_amdgcn_sched_barrier(0);
    }
  } else {
    // depth-2, counted vmcnt (loads/stage = 4 + TN/32 = 8 for TN=128)
    stage(0, 0);
    if (nt > 1) stage(1, 64);
    if (nt > 1) asm volatile("s_waitcnt vmcnt(8)" ::: "memory");
    else asm volatile("s_waitcnt vmcnt(0)" ::: "memory");
    __builtin_amdgcn_s_barrier();
    for (int t = 0; t < nt; ++t) {
      const int cur = t % 3;
      if (t + 2 < nt) stage((t + 2) % 3, (t + 2) << 6);
      compute(cur);
      if (t + 1 < nt) {
        if (t + 2 < nt) asm volatile("s_waitcnt vmcnt(8)" ::: "memory");
        else asm volatile("s_waitcnt vmcnt(0)" ::: "memory");
        __builtin_amdgcn_sched_barrier(0);
        __builtin_amdgcn_s_barrier();
        __builtin_amdgcn_sched_barrier(0);
      }
    }
    __syncthreads();  // ensure all waves done before epilogue reuses As
  }

  if constexpr (MODE >= 5) {
#pragma unroll
    for (int m = 0; m < 4; ++m) {
#pragma unroll
      for (int n = 0; n < NR; ++n) {
        int c = bj * TN + wc * (TN / 2) + n * 16 + fr;
#pragma unroll
        for (int j = 0; j < 4; ++j) {
          int r = bi * 128 + wr * 64 + m * 16 + fg * 4 + j;
          float v = acc[m][n][j];
          if constexpr (MODE == 5) {
            fout[(size_t)r * 512 + c] = v + fbias[c];
          } else {
            if (c < OUT_DIM) fout[(size_t)r * OUT_DIM + c] = v + fbias[c];
          }
        }
      }
    }
  } else {
    // LDS-staged coalesced epilogue
    bf16* stg = &As[0][0];
#pragma unroll
    for (int m = 0; m < 4; ++m)
#pragma unroll
      for (int n = 0; n < NR; ++n) {
        int lc = wc * (TN / 2) + n * 16 + fr;
#pragma unroll
        for (int j = 0; j < 4; ++j) {
          int lr = wr * 64 + m * 16 + fg * 4 + j;
          float v = acc[m][n][j];
          if constexpr (MODE == 3) v = fmaxf(v, 0.f);
          stg[lr * TN + lc] = (bf16)v;
        }
      }
    __syncthreads();
    constexpr int TPR = TN / 8;
    constexpr int RSTEP = 256 / TPR;
    const int c8 = (tid % TPR) * 8;
    const int lr0 = tid / TPR;
#pragma unroll
    for (int lr = lr0; lr < 128; lr += RSTEP) {
      bf16x8 v = *(const bf16x8*)&stg[lr * TN + c8];
      int r = bi * 128 + lr;
      int c = bj * TN + c8;
      if constexpr (MODE == 1) {
        bf16x8 o;
#pragma unroll
        for (int k = 0; k < 8; ++k) o[k] = (c + k < r) ? v[k] : (bf16)0.f;
        *(bf16x8*)&bout[((size_t)zz << 20) + (size_t)r * T_SEQ + c] = o;
      } else if constexpr (MODE == 2) {
        *(bf16x8*)&bout[((size_t)zz << 19) + (size_t)r * 512 + c] = v;
      } else if constexpr (MODE == 3) {
        bf16x8 g = *(const bf16x8*)&aux[((size_t)zz << 21) + (size_t)r * N_INT + c];
        bf16x8 o;
#pragma unroll
        for (int k = 0; k < 8; ++k) o[k] = (bf16)((float)v[k] * (float)g[k]);
        *(bf16x8*)&bout[((size_t)(zz >> 3) << 24) + (size_t)r * 16384 + (size_t)(zz & 7) * N_INT + c] = o;
      } else {
        *(bf16x8*)&bout[((size_t)cb << 19) + (size_t)r * 512 + c] = v;
      }
    }
  }
}

__global__ __launch_bounds__(256, 3) void g_scores(const bf16* A, bf16* o) {
  gemm_body<1, 64, 1>(A, nullptr, nullptr, nullptr, nullptr, o);
}
__global__ __launch_bounds__(256, 3) void g_pv(const bf16* A, const bf16* B, bf16* o) {
  gemm_body<2, 64, 1>(A, B, nullptr, nullptr, nullptr, o);
}
__global__ __launch_bounds__(256) void g_gate(const bf16* A, const bf16* B, const bf16* aux, bf16* o) {
  gemm_body<3, 128, 2>(A, B, aux, nullptr, nullptr, o);  // depth-2 counted vmcnt (96 KB LDS)
}
__global__ __launch_bounds__(256, 2) void g_dec(const bf16* A, const bf16* B, bf16* o) {
  gemm_body<4, 128, 1>(A, B, nullptr, nullptr, nullptr, o);
}
__global__ __launch_bounds__(256, 2) void g_in(const bf16* A, const bf16* B, const float* bias, float* o) {
  gemm_body<5, 128, 1>(A, B, nullptr, bias, o, nullptr);
}
__global__ __launch_bounds__(256, 2) void g_out(const bf16* A, const bf16* B, const float* bias, float* o) {
  gemm_body<6, 128, 1>(A, B, nullptr, bias, o, nullptr);
}

// ---------- fused hsp+RoPE GEMM: batch-merged, 128(M) x 64-pair(N) ----------
__global__ __launch_bounds__(256, 2) void g_hspr(const bf16* __restrict__ hbf,
                                                 const bf16* __restrict__ encT,
                                                 const h16x2* __restrict__ cs,
                                                 bf16* __restrict__ hsp,
                                                 bf16* __restrict__ qr) {
  const int id = blockIdx.x;
  const int zz = id & 15;  // b*8+h
  const int r_ = id >> 4;
  const int bi = r_ & 7;   // 8 M-tiles of 128
  const int bj = r_ >> 3;  // 16 N-pair tiles of 64

  const bf16* B0 = encT + (size_t)(zz & 7) * N_INT * 512 + (size_t)(bj * 64) * 512;
  const bf16* B1 = B0 + (size_t)1024 * 512;
  const bf16* hbf_b = hbf + (size_t)(zz >> 3) * T_SEQ * 512;

  const int tid = threadIdx.x;
  const int trow = tid >> 3, tq = tid & 7;
  const int sq = tq ^ (trow & 7);
  const bf16* ags = hbf_b + (size_t)(bi * 128 + trow) * 512 + sq * 8;
  const bf16* bgs0 = B0 + (size_t)trow * 512 + sq * 8;
  const bf16* bgs1 = B1 + (size_t)trow * 512 + sq * 8;

  __shared__ __align__(16) bf16 As[2][128 * 64];
  __shared__ __align__(16) bf16 Bs[2][2 * 64 * 64];
  const int so = tid * 8;

  const int lane = tid & 63, wid = tid >> 6;
  const int wr = wid >> 1, wc = wid & 1;
  const int fr = lane & 15, fg = lane >> 4;
  const int axor = fr & 7;

  f32x4 acc[4][2][2] = {};

  auto stage = [&](int buf, int kk) {
#pragma unroll
    for (int p = 0; p < 4; ++p)
      gld16(ags + (size_t)(p * 32) * 512 + kk, &As[buf][p * 2048 + so]);
    gld16(bgs0 + kk, &Bs[buf][0 * 2048 + so]);
    gld16(bgs0 + (size_t)32 * 512 + kk, &Bs[buf][1 * 2048 + so]);
    gld16(bgs1 + kk, &Bs[buf][2 * 2048 + so]);
    gld16(bgs1 + (size_t)32 * 512 + kk, &Bs[buf][3 * 2048 + so]);
  };

  stage(0, 0);
  asm volatile("s_waitcnt vmcnt(0)" ::: "memory");
  __builtin_amdgcn_s_barrier();

  for (int t = 0; t < 8; ++t) {
    const int cur = t & 1;
    if (t + 1 < 8) stage(cur ^ 1, (t + 1) << 6);

    __builtin_amdgcn_s_setprio(1);
#pragma unroll
    for (int s = 0; s < 2; ++s) {
      bf16x8 af[4], bfv[2][2];
#pragma unroll
      for (int m = 0; m < 4; ++m)
        af[m] = *(const bf16x8*)(&As[cur][(wr * 64 + m * 16 + fr) * 64 + (((s * 4 + fg) ^ axor) * 8)]);
#pragma unroll
      for (int pp = 0; pp < 2; ++pp)
#pragma unroll
        for (int n = 0; n < 2; ++n)
          bfv[pp][n] = *(const bf16x8*)(&Bs[cur][pp * 4096 + (wc * 32 + n * 16 + fr) * 64 + (((s * 4 + fg) ^ axor) * 8)]);
#pragma unroll
      for (int m = 0; m < 4; ++m)
#pragma unroll
        for (int n = 0; n < 2; ++n)
#pragma unroll
          for (int pp = 0; pp < 2; ++pp)
            acc[m][n][pp] = __builtin_amdgcn_mfma_f32_16x16x32_bf16(af[m], bfv[pp][n], acc[m][n][pp], 0, 0, 0);
    }
    __builtin_amdgcn_s_setprio(0);

    asm volatile("s_waitcnt vmcnt(0)" ::: "memory");
    __builtin_amdgcn_sched_barrier(0);
    __builtin_amdgcn_s_barrier();
    __builtin_amdgcn_sched_barrier(0);
  }

  // staged epilogue: sL/sH = relu(lo/hi panel); qr derived on write
  bf16* sL = &As[0][0];
  bf16* sH = &As[1][0];
#pragma unroll
  for (int m = 0; m < 4; ++m)
#pragma unroll
    for (int n = 0; n < 2; ++n) {
      int lc = wc * 32 + n * 16 + fr;
#pragma unroll
      for (int j = 0; j < 4; ++j) {
        int lr = wr * 64 + m * 16 + fg * 4 + j;
        sL[lr * 64 + lc] = (bf16)fmaxf(acc[m][n][0][j], 0.f);
        sH[lr * 64 + lc] = (bf16)fmaxf(acc[m][n][1][j], 0.f);
      }
    }
  __syncthreads();

  const size_t hb = (size_t)zz * T_SEQ;
  const int c8 = (tid & 7) * 8;
  const int lr0 = tid >> 3;
#pragma unroll
  for (int lr = lr0; lr < 128; lr += 32) {
    int r = bi * 128 + lr;
    int c = bj * 64 + c8;
    bf16x8 lo = *(const bf16x8*)&sL[lr * 64 + c8];
    bf16x8 hi = *(const bf16x8*)&sH[lr * 64 + c8];
    size_t base = (hb + r) * N_INT + c;
    *(bf16x8*)&hsp[base] = lo;
    *(bf16x8*)&hsp[base + 1024] = hi;
    const h16x2* csp = &cs[(size_t)r * 1024 + c];
    bf16x8 qlo, qhi;
#pragma unroll
    for (int k = 0; k < 8; ++k) {
      h16x2 p = csp[k];
      float co = (float)p[0], si = (float)p[1];
      float v0 = (float)lo[k], v1 = (float)hi[k];
      qlo[k] = (bf16)(v0 * co - v1 * si);
      qhi[k] = (bf16)(v1 * co + v0 * si);
    }
    *(bf16x8*)&qr[base] = qlo;
    *(bf16x8*)&qr[base + 1024] = qhi;
  }
}

// ---------- launch ----------
extern "C" void kernel_launch(void* const* d_in, const int* in_sizes, int n_in,
                              void* d_out, int out_size, void* d_ws, size_t ws_size,
                              hipStream_t stream) {
  const float* x = (const float*)d_in[0];
  const float* Wi = (const float*)d_in[1];
  const float* bi = (const float*)d_in[2];
  const float* enc = (const float*)d_in[3];
  const float* encv = (const float*)d_in[4];
  const float* dec = (const float*)d_in[5];
  const float* Wo = (const float*)d_in[6];
  const float* bo = (const float*)d_in[7];
  float* out = (float*)d_out;

  const size_t NEED = 253000000;
  if (ws_size < NEED) return;

  char* w = (char*)d_ws;
  auto alloc = [&](size_t bytes) {
    char* p = w;
    w += (bytes + 255) & ~(size_t)255;
    return p;
  };
  bf16* encT = (bf16*)alloc((size_t)NHEADS * N_INT * 512 * 2);
  bf16* encvT = (bf16*)alloc((size_t)NHEADS * N_INT * 512 * 2);
  bf16* decT = (bf16*)alloc((size_t)512 * 16384 * 2);
  h16x2* cs = (h16x2*)alloc((size_t)T_SEQ * 1024 * 4);
  float* h = (float*)alloc((size_t)2048 * 512 * 4);
  bf16* hbf = (bf16*)alloc((size_t)2048 * 512 * 2);
  bf16* hT = (bf16*)alloc((size_t)2048 * 512 * 2);
  bf16* hsp = (bf16*)alloc((size_t)2 * NHEADS * T_SEQ * N_INT * 2);
  bf16* qr = (bf16*)alloc((size_t)2 * NHEADS * T_SEQ * N_INT * 2);
  bf16* S = (bf16*)alloc((size_t)2 * NHEADS * T_SEQ * T_SEQ * 2);
  bf16* ykv = (bf16*)alloc((size_t)2 * NHEADS * T_SEQ * 512 * 2);
  float* zbuf = (float*)alloc((size_t)2048 * 512 * 4);
  bf16* WoT = (bf16*)alloc((size_t)OUT_PAD * 512 * 2);
  bf16* xbf = S;
  bf16* WiT = S + 1048576;

  transpose_cvt<<<dim3(64, 16, 8), dim3(32, 8), 0, stream>>>(enc, encT, 512, N_INT);
  transpose_cvt<<<dim3(64, 16, 8), dim3(32, 8), 0, stream>>>(encv, encvT, 512, N_INT);
  transpose_cvt<<<dim3(16, 512, 1), dim3(32, 8), 0, stream>>>(dec, decT, 16384, 512);
  pad_trans<<<dim3(16, 12), dim3(32, 8), 0, stream>>>(Wi, WiT, IN_DIM, 512, IN_PAD);
  pad_trans<<<dim3(8, 16), dim3(32, 8), 0, stream>>>(Wo, WoT, 512, OUT_DIM, 512);
  cvt_pad_x<<<2048, 256, 0, stream>>>(x, xbf);
  rope_tables<<<1024, 256, 0, stream>>>(cs);
  g_in<<<64, 256, 0, stream>>>(xbf, WiT, bi, zbuf);
  ln0<<<2048, 256, 0, stream>>>(zbuf, h, hbf, hT);

  for (int L = 0; L < 3; ++L) {
    g_hspr<<<2048, 256, 0, stream>>>(hbf, encT, cs, hsp, qr);
    g_scores<<<1152, 256, 0, stream>>>(qr, S);
    g_pv<<<1024, 256, 0, stream>>>(S, hT, ykv);
    ln_rows<<<4096, 256, 0, stream>>>(ykv);
    g_gate<<<2048, 256, 0, stream>>>(ykv, encvT, hsp, qr);
    g_dec<<<512, 256, 0, stream>>>(qr, decT, S);
    psum_lnd<<<2048, 256, 0, stream>>>(S, h, hbf, hT);
  }
  g_out<<<32, 256, 0, stream>>>(hbf, WoT, bo, out);
}

// Round 18
// 835.598 us; speedup vs baseline: 1.1052x; 1.1052x over previous
//
#include <hip/hip_runtime.h>

// ---------- types ----------
typedef __bf16 bf16;
typedef __attribute__((ext_vector_type(8))) __bf16 bf16x8;
typedef __attribute__((ext_vector_type(4))) float f32x4;
typedef __attribute__((ext_vector_type(2))) _Float16 h16x2;

#define T_SEQ 1024
#define D_MODEL 512
#define N_INT 2048
#define NHEADS 8
#define IN_DIM 372
#define IN_PAD 384
#define OUT_DIM 186
#define OUT_PAD 256

__device__ inline void gld16(const bf16* g, bf16* l) {
  __builtin_amdgcn_global_load_lds((const __attribute__((address_space(1))) void*)g,
                                   (__attribute__((address_space(3))) void*)l, 16, 0, 0);
}

// block-wide sum of two values (256 threads)
__device__ inline void block_sum2(float& a, float& b, float* red) {
#pragma unroll
  for (int o = 32; o > 0; o >>= 1) {
    a += __shfl_down(a, o, 64);
    b += __shfl_down(b, o, 64);
  }
  __syncthreads();
  if ((threadIdx.x & 63) == 0) {
    int w = threadIdx.x >> 6;
    red[2 * w] = a;
    red[2 * w + 1] = b;
  }
  __syncthreads();
  a = red[0] + red[2] + red[4] + red[6];
  b = red[1] + red[3] + red[5] + red[7];
}

// ---------- transpose + fp32->bf16 convert ----------
__global__ __launch_bounds__(256) void transpose_cvt(const float* __restrict__ in,
                                                     bf16* __restrict__ out,
                                                     int rows, int cols) {
  __shared__ float tile[32][33];
  size_t zoff = (size_t)blockIdx.z * rows * cols;
  in += zoff;
  out += zoff;
  int c0 = blockIdx.x * 32, r0 = blockIdx.y * 32;
#pragma unroll
  for (int i = threadIdx.y; i < 32; i += 8)
    tile[i][threadIdx.x] = in[(size_t)(r0 + i) * cols + c0 + threadIdx.x];
  __syncthreads();
#pragma unroll
  for (int i = threadIdx.y; i < 32; i += 8)
    out[(size_t)(c0 + i) * rows + r0 + threadIdx.x] = (bf16)tile[threadIdx.x][i];
}

// ---------- zero-padded transpose + cvt ----------
__global__ __launch_bounds__(256) void pad_trans(const float* __restrict__ in,
                                                 bf16* __restrict__ out,
                                                 int R, int C, int outLd) {
  __shared__ float tile[32][33];
  int c0 = blockIdx.x * 32, r0 = blockIdx.y * 32;
#pragma unroll
  for (int i = threadIdx.y; i < 32; i += 8) {
    int r = r0 + i, c = c0 + threadIdx.x;
    tile[i][threadIdx.x] = (r < R && c < C) ? in[(size_t)r * C + c] : 0.f;
  }
  __syncthreads();
#pragma unroll
  for (int i = threadIdx.y; i < 32; i += 8)
    out[(size_t)(c0 + i) * outLd + r0 + threadIdx.x] = (bf16)tile[threadIdx.x][i];
}

// ---------- x fp32 [2048][372] -> xbf bf16 [2048][384] zero-padded ----------
__global__ __launch_bounds__(256) void cvt_pad_x(const float* __restrict__ x,
                                                 bf16* __restrict__ xbf) {
  size_t r = blockIdx.x;
  for (int c = threadIdx.x; c < IN_PAD; c += 256)
    xbf[r * IN_PAD + c] = (c < IN_DIM) ? (bf16)x[r * IN_DIM + c] : (bf16)0.f;
}

// ---------- RoPE table: packed fp16 (cos,sin) per (t,i) ----------
__global__ __launch_bounds__(256) void rope_tables(h16x2* __restrict__ cs) {
  int t = blockIdx.x;
  for (int i = threadIdx.x; i < 1024; i += 256) {
    float ph = (float)t * exp2f(-16.0f * (float)i * (1.0f / 1024.0f));
    h16x2 v;
    v[0] = (_Float16)cosf(ph);
    v[1] = (_Float16)sinf(ph);
    cs[(size_t)t * 1024 + i] = v;
  }
}

// ---------- ln0: h = LN(z) ----------
__global__ __launch_bounds__(256) void ln0(const float* __restrict__ zin,
                                           float* __restrict__ h, bf16* __restrict__ hbf,
                                           bf16* __restrict__ hT) {
  __shared__ float red[8];
  size_t r = blockIdx.x;
  int tid = threadIdx.x;
  float v0 = zin[r * 512 + tid], v1 = zin[r * 512 + tid + 256];
  float s = v0 + v1, s2 = v0 * v0 + v1 * v1;
  block_sum2(s, s2, red);
  float mean = s * (1.f / 512.f);
  float var = s2 * (1.f / 512.f) - mean * mean;
  float rs = rsqrtf(var + 1e-5f);
  float o0 = (v0 - mean) * rs, o1 = (v1 - mean) * rs;
  h[r * 512 + tid] = o0;
  h[r * 512 + tid + 256] = o1;
  hbf[r * 512 + tid] = (bf16)o0;
  hbf[r * 512 + tid + 256] = (bf16)o1;
  int b = (int)(r >> 10), t = (int)(r & (T_SEQ - 1));
  hT[((size_t)b * 512 + tid) * T_SEQ + t] = (bf16)o0;
  hT[((size_t)b * 512 + tid + 256) * T_SEQ + t] = (bf16)o1;
}

// ---------- wave-per-row in-place LN on bf16 rows of 512 (4 rows/block) ----------
__global__ __launch_bounds__(256) void ln_rows(bf16* __restrict__ io) {
  const int wid = threadIdx.x >> 6, lane = threadIdx.x & 63;
  size_t r = (size_t)blockIdx.x * 4 + wid;
  bf16* p = io + r * 512 + lane * 8;
  bf16x8 v = *(const bf16x8*)p;
  float f[8], s = 0.f, s2 = 0.f;
#pragma unroll
  for (int j = 0; j < 8; ++j) {
    f[j] = (float)v[j];
    s += f[j];
    s2 += f[j] * f[j];
  }
#pragma unroll
  for (int o = 32; o > 0; o >>= 1) {
    s += __shfl_xor(s, o, 64);
    s2 += __shfl_xor(s2, o, 64);
  }
  float mean = s * (1.f / 512.f);
  float var = s2 * (1.f / 512.f) - mean * mean;
  float rs = rsqrtf(var + 1e-5f);
  bf16x8 o;
#pragma unroll
  for (int j = 0; j < 8; ++j) o[j] = (bf16)((f[j] - mean) * rs);
  *(bf16x8*)p = o;
}

// ---------- fused: z=sum(8 partials of batch b); h=LN(h_res+LN(z)) ----------
__global__ __launch_bounds__(256) void psum_lnd(const bf16* __restrict__ part,
                                                float* __restrict__ h, bf16* __restrict__ hbf,
                                                bf16* __restrict__ hT) {
  __shared__ float red[8];
  int b = blockIdx.x >> 10;
  int r = blockIdx.x & 1023;
  int tid = threadIdx.x;
  float z0 = 0.f, z1 = 0.f;
#pragma unroll
  for (int k = 0; k < 8; ++k) {
    size_t off = ((size_t)(b * 8 + k) << 19) + (size_t)r * 512;
    z0 += (float)part[off + tid];
    z1 += (float)part[off + tid + 256];
  }
  float s = z0 + z1, s2 = z0 * z0 + z1 * z1;
  block_sum2(s, s2, red);
  float m1 = s * (1.f / 512.f);
  float v1_ = s2 * (1.f / 512.f) - m1 * m1;
  float rs1 = rsqrtf(v1_ + 1e-5f);
  size_t R = (size_t)b * T_SEQ + r;
  float a0 = (z0 - m1) * rs1 + h[R * 512 + tid];
  float a1 = (z1 - m1) * rs1 + h[R * 512 + tid + 256];
  s = a0 + a1;
  s2 = a0 * a0 + a1 * a1;
  block_sum2(s, s2, red);
  float m2 = s * (1.f / 512.f);
  float v2_ = s2 * (1.f / 512.f) - m2 * m2;
  float rs2 = rsqrtf(v2_ + 1e-5f);
  float o0 = (a0 - m2) * rs2, o1 = (a1 - m2) * rs2;
  h[R * 512 + tid] = o0;
  h[R * 512 + tid + 256] = o1;
  hbf[R * 512 + tid] = (bf16)o0;
  hbf[R * 512 + tid + 256] = (bf16)o1;
  hT[((size_t)b * 512 + tid) * T_SEQ + r] = (bf16)o0;
  hT[((size_t)b * 512 + tid + 256) * T_SEQ + r] = (bf16)o1;
}

// ==================================================================
// 128(M) x TN(N) MFMA GEMM, batch-merged (zz = id&15 = b*8+h).
// r9-proven single-barrier 2-phase K-loop (drain-0, depth-1 — depth-2
// REGRESSED in r17: lost block-TLP outweighs counted-vmcnt cover).
// LDS-staged coalesced epilogue. XOR-swizzle (T2). XCD pin (T1).
// Per-kernel measured-optimal geometry: short-K (gate/dec) TN=128 @2
// blocks/CU; long-K (scores/pv) TN=64 @3 blocks/CU.
// MODE 4: split-K-8, chunks of K=2048, chunk pinned to XCD chunk%8.
// ==================================================================
template <int MODE, int TN>
__device__ __forceinline__ void gemm_body(const bf16* __restrict__ Abase,
                                          const bf16* __restrict__ Bbase,
                                          const bf16* __restrict__ aux,
                                          const float* __restrict__ fbias,
                                          float* __restrict__ fout,
                                          bf16* __restrict__ bout) {
  const int id = blockIdx.x;
  int zz = 0, r_, cb = 0;
  if constexpr (MODE >= 5) {
    r_ = id;
  } else if constexpr (MODE == 4) {
    cb = id & 15;   // b*8+chunk; chunk pinned to XCD chunk%8
    r_ = id >> 4;   // 0..31 = bi(8) x bj(4)
  } else {
    zz = id & 15;   // b*8+h  (head pinned to XCD h%8)
    r_ = id >> 4;
  }
  int bi, bj;
  if constexpr (MODE == 1) {
    int l = r_;  // l = bi*(bi+1)+bj, 72 tiles
    bi = (int)sqrtf((float)l);
    while ((bi + 1) * (bi + 2) <= l) ++bi;
    while (bi * (bi + 1) > l) --bi;
    bj = l - bi * (bi + 1);
  } else if constexpr (MODE >= 5) {
    bi = r_ & 15;
    bj = r_ >> 4;
  } else {
    bi = r_ & 7;
    bj = r_ >> 3;
  }

  const bf16* A;
  const bf16* Bt;
  int lda, ldb, kend;
  if constexpr (MODE == 1) {
    A = Abase + ((size_t)zz << 21); lda = N_INT;  // qr[b][h][1024][2048]
    Bt = A; ldb = N_INT;
    kend = N_INT;
  } else if constexpr (MODE == 2) {
    A = Abase + ((size_t)zz << 20); lda = T_SEQ;  // S[b][h][1024][1024]
    Bt = Bbase + (size_t)(zz >> 3) * 512 * T_SEQ; ldb = T_SEQ;
    kend = (bi + 1) * 128;
  } else if constexpr (MODE == 3) {
    A = Abase + ((size_t)zz << 19); lda = 512;    // ykv[b][h][1024][512]
    Bt = Bbase + (size_t)(zz & 7) * N_INT * 512; ldb = 512;
    kend = 512;
  } else if constexpr (MODE == 4) {
    A = Abase + ((size_t)(cb >> 3) << 24) + (size_t)(cb & 7) * 2048; lda = 16384;
    Bt = Bbase + (size_t)(cb & 7) * 2048; ldb = 16384;
    kend = 2048;
  } else if constexpr (MODE == 5) {
    A = Abase; lda = IN_PAD;
    Bt = Bbase; ldb = IN_PAD;
    kend = IN_PAD;
  } else {
    A = Abase; lda = 512;
    Bt = Bbase; ldb = 512;
    kend = 512;
  }

  const int tid = threadIdx.x;
  const int trow = tid >> 3, tq = tid & 7;
  const int sq = tq ^ (trow & 7);
  const bf16* ags = A + (size_t)(bi * 128 + trow) * lda + sq * 8;
  const bf16* bgs = Bt + (size_t)(bj * TN + trow) * ldb + sq * 8;

  __shared__ __align__(16) bf16 As[2][128 * 64];
  __shared__ __align__(16) bf16 Bs[2][TN * 64];
  const int so = tid * 8;

  const int lane = tid & 63, wid = tid >> 6;
  const int wr = wid >> 1, wc = wid & 1;
  const int fr = lane & 15, fg = lane >> 4;
  const int axor = fr & 7;
  constexpr int NR = TN / 32;

  f32x4 acc[4][NR] = {};

  auto stage = [&](int buf, int kk) {
#pragma unroll
    for (int p = 0; p < 4; ++p)
      gld16(ags + (size_t)(p * 32) * lda + kk, &As[buf][p * 2048 + so]);
#pragma unroll
    for (int p = 0; p < TN / 32; ++p)
      gld16(bgs + (size_t)(p * 32) * ldb + kk, &Bs[buf][p * 2048 + so]);
  };

  const int nt = kend >> 6;
  stage(0, 0);
  asm volatile("s_waitcnt vmcnt(0)" ::: "memory");
  __builtin_amdgcn_s_barrier();

  for (int t = 0; t < nt; ++t) {
    const int cur = t & 1;
    if (t + 1 < nt) stage(cur ^ 1, (t + 1) << 6);

    __builtin_amdgcn_s_setprio(1);
#pragma unroll
    for (int s = 0; s < 2; ++s) {
      bf16x8 af[4], bfv[NR];
#pragma unroll
      for (int m = 0; m < 4; ++m)
        af[m] = *(const bf16x8*)(&As[cur][(wr * 64 + m * 16 + fr) * 64 + (((s * 4 + fg) ^ axor) * 8)]);
#pragma unroll
      for (int n = 0; n < NR; ++n)
        bfv[n] = *(const bf16x8*)(&Bs[cur][(wc * (TN / 2) + n * 16 + fr) * 64 + (((s * 4 + fg) ^ axor) * 8)]);
#pragma unroll
      for (int m = 0; m < 4; ++m)
#pragma unroll
        for (int n = 0; n < NR; ++n)
          acc[m][n] = __builtin_amdgcn_mfma_f32_16x16x32_bf16(af[m], bfv[n], acc[m][n], 0, 0, 0);
    }
    __builtin_amdgcn_s_setprio(0);

    asm volatile("s_waitcnt vmcnt(0)" ::: "memory");
    __builtin_amdgcn_sched_barrier(0);
    __builtin_amdgcn_s_barrier();
    __builtin_amdgcn_sched_barrier(0);
  }

  if constexpr (MODE >= 5) {
#pragma unroll
    for (int m = 0; m < 4; ++m) {
#pragma unroll
      for (int n = 0; n < NR; ++n) {
        int c = bj * TN + wc * (TN / 2) + n * 16 + fr;
#pragma unroll
        for (int j = 0; j < 4; ++j) {
          int r = bi * 128 + wr * 64 + m * 16 + fg * 4 + j;
          float v = acc[m][n][j];
          if constexpr (MODE == 5) {
            fout[(size_t)r * 512 + c] = v + fbias[c];
          } else {
            if (c < OUT_DIM) fout[(size_t)r * OUT_DIM + c] = v + fbias[c];
          }
        }
      }
    }
  } else {
    // LDS-staged coalesced epilogue
    bf16* stg = &As[0][0];
#pragma unroll
    for (int m = 0; m < 4; ++m)
#pragma unroll
      for (int n = 0; n < NR; ++n) {
        int lc = wc * (TN / 2) + n * 16 + fr;
#pragma unroll
        for (int j = 0; j < 4; ++j) {
          int lr = wr * 64 + m * 16 + fg * 4 + j;
          float v = acc[m][n][j];
          if constexpr (MODE == 3) v = fmaxf(v, 0.f);
          stg[lr * TN + lc] = (bf16)v;
        }
      }
    __syncthreads();
    constexpr int TPR = TN / 8;
    constexpr int RSTEP = 256 / TPR;
    const int c8 = (tid % TPR) * 8;
    const int lr0 = tid / TPR;
#pragma unroll
    for (int lr = lr0; lr < 128; lr += RSTEP) {
      bf16x8 v = *(const bf16x8*)&stg[lr * TN + c8];
      int r = bi * 128 + lr;
      int c = bj * TN + c8;
      if constexpr (MODE == 1) {
        bf16x8 o;
#pragma unroll
        for (int k = 0; k < 8; ++k) o[k] = (c + k < r) ? v[k] : (bf16)0.f;
        *(bf16x8*)&bout[((size_t)zz << 20) + (size_t)r * T_SEQ + c] = o;
      } else if constexpr (MODE == 2) {
        *(bf16x8*)&bout[((size_t)zz << 19) + (size_t)r * 512 + c] = v;
      } else if constexpr (MODE == 3) {
        bf16x8 g = *(const bf16x8*)&aux[((size_t)zz << 21) + (size_t)r * N_INT + c];
        bf16x8 o;
#pragma unroll
        for (int k = 0; k < 8; ++k) o[k] = (bf16)((float)v[k] * (float)g[k]);
        *(bf16x8*)&bout[((size_t)(zz >> 3) << 24) + (size_t)r * 16384 + (size_t)(zz & 7) * N_INT + c] = o;
      } else {
        *(bf16x8*)&bout[((size_t)cb << 19) + (size_t)r * 512 + c] = v;
      }
    }
  }
}

__global__ __launch_bounds__(256, 3) void g_scores(const bf16* A, bf16* o) {
  gemm_body<1, 64>(A, nullptr, nullptr, nullptr, nullptr, o);
}
__global__ __launch_bounds__(256, 3) void g_pv(const bf16* A, const bf16* B, bf16* o) {
  gemm_body<2, 64>(A, B, nullptr, nullptr, nullptr, o);
}
__global__ __launch_bounds__(256, 2) void g_gate(const bf16* A, const bf16* B, const bf16* aux, bf16* o) {
  gemm_body<3, 128>(A, B, aux, nullptr, nullptr, o);  // measured-best: TN=128, depth-1, 2 blocks/CU
}
__global__ __launch_bounds__(256, 2) void g_dec(const bf16* A, const bf16* B, bf16* o) {
  gemm_body<4, 128>(A, B, nullptr, nullptr, nullptr, o);  // split-K-8, K=2048 chunks
}
__global__ __launch_bounds__(256, 2) void g_in(const bf16* A, const bf16* B, const float* bias, float* o) {
  gemm_body<5, 128>(A, B, nullptr, bias, o, nullptr);
}
__global__ __launch_bounds__(256, 2) void g_out(const bf16* A, const bf16* B, const float* bias, float* o) {
  gemm_body<6, 128>(A, B, nullptr, bias, o, nullptr);
}

// ---------- fused hsp+RoPE GEMM: batch-merged, 128(M) x 64-pair(N) ----------
__global__ __launch_bounds__(256, 2) void g_hspr(const bf16* __restrict__ hbf,
                                                 const bf16* __restrict__ encT,
                                                 const h16x2* __restrict__ cs,
                                                 bf16* __restrict__ hsp,
                                                 bf16* __restrict__ qr) {
  const int id = blockIdx.x;
  const int zz = id & 15;  // b*8+h
  const int r_ = id >> 4;
  const int bi = r_ & 7;   // 8 M-tiles of 128
  const int bj = r_ >> 3;  // 16 N-pair tiles of 64

  const bf16* B0 = encT + (size_t)(zz & 7) * N_INT * 512 + (size_t)(bj * 64) * 512;
  const bf16* B1 = B0 + (size_t)1024 * 512;
  const bf16* hbf_b = hbf + (size_t)(zz >> 3) * T_SEQ * 512;

  const int tid = threadIdx.x;
  const int trow = tid >> 3, tq = tid & 7;
  const int sq = tq ^ (trow & 7);
  const bf16* ags = hbf_b + (size_t)(bi * 128 + trow) * 512 + sq * 8;
  const bf16* bgs0 = B0 + (size_t)trow * 512 + sq * 8;
  const bf16* bgs1 = B1 + (size_t)trow * 512 + sq * 8;

  __shared__ __align__(16) bf16 As[2][128 * 64];
  __shared__ __align__(16) bf16 Bs[2][2 * 64 * 64];
  const int so = tid * 8;

  const int lane = tid & 63, wid = tid >> 6;
  const int wr = wid >> 1, wc = wid & 1;
  const int fr = lane & 15, fg = lane >> 4;
  const int axor = fr & 7;

  f32x4 acc[4][2][2] = {};

  auto stage = [&](int buf, int kk) {
#pragma unroll
    for (int p = 0; p < 4; ++p)
      gld16(ags + (size_t)(p * 32) * 512 + kk, &As[buf][p * 2048 + so]);
    gld16(bgs0 + kk, &Bs[buf][0 * 2048 + so]);
    gld16(bgs0 + (size_t)32 * 512 + kk, &Bs[buf][1 * 2048 + so]);
    gld16(bgs1 + kk, &Bs[buf][2 * 2048 + so]);
    gld16(bgs1 + (size_t)32 * 512 + kk, &Bs[buf][3 * 2048 + so]);
  };

  stage(0, 0);
  asm volatile("s_waitcnt vmcnt(0)" ::: "memory");
  __builtin_amdgcn_s_barrier();

  for (int t = 0; t < 8; ++t) {
    const int cur = t & 1;
    if (t + 1 < 8) stage(cur ^ 1, (t + 1) << 6);

    __builtin_amdgcn_s_setprio(1);
#pragma unroll
    for (int s = 0; s < 2; ++s) {
      bf16x8 af[4], bfv[2][2];
#pragma unroll
      for (int m = 0; m < 4; ++m)
        af[m] = *(const bf16x8*)(&As[cur][(wr * 64 + m * 16 + fr) * 64 + (((s * 4 + fg) ^ axor) * 8)]);
#pragma unroll
      for (int pp = 0; pp < 2; ++pp)
#pragma unroll
        for (int n = 0; n < 2; ++n)
          bfv[pp][n] = *(const bf16x8*)(&Bs[cur][pp * 4096 + (wc * 32 + n * 16 + fr) * 64 + (((s * 4 + fg) ^ axor) * 8)]);
#pragma unroll
      for (int m = 0; m < 4; ++m)
#pragma unroll
        for (int n = 0; n < 2; ++n)
#pragma unroll
          for (int pp = 0; pp < 2; ++pp)
            acc[m][n][pp] = __builtin_amdgcn_mfma_f32_16x16x32_bf16(af[m], bfv[pp][n], acc[m][n][pp], 0, 0, 0);
    }
    __builtin_amdgcn_s_setprio(0);

    asm volatile("s_waitcnt vmcnt(0)" ::: "memory");
    __builtin_amdgcn_sched_barrier(0);
    __builtin_amdgcn_s_barrier();
    __builtin_amdgcn_sched_barrier(0);
  }

  // staged epilogue: sL/sH = relu(lo/hi panel); qr derived on write
  bf16* sL = &As[0][0];
  bf16* sH = &As[1][0];
#pragma unroll
  for (int m = 0; m < 4; ++m)
#pragma unroll
    for (int n = 0; n < 2; ++n) {
      int lc = wc * 32 + n * 16 + fr;
#pragma unroll
      for (int j = 0; j < 4; ++j) {
        int lr = wr * 64 + m * 16 + fg * 4 + j;
        sL[lr * 64 + lc] = (bf16)fmaxf(acc[m][n][0][j], 0.f);
        sH[lr * 64 + lc] = (bf16)fmaxf(acc[m][n][1][j], 0.f);
      }
    }
  __syncthreads();

  const size_t hb = (size_t)zz * T_SEQ;
  const int c8 = (tid & 7) * 8;
  const int lr0 = tid >> 3;
#pragma unroll
  for (int lr = lr0; lr < 128; lr += 32) {
    int r = bi * 128 + lr;
    int c = bj * 64 + c8;
    bf16x8 lo = *(const bf16x8*)&sL[lr * 64 + c8];
    bf16x8 hi = *(const bf16x8*)&sH[lr * 64 + c8];
    size_t base = (hb + r) * N_INT + c;
    *(bf16x8*)&hsp[base] = lo;
    *(bf16x8*)&hsp[base + 1024] = hi;
    const h16x2* csp = &cs[(size_t)r * 1024 + c];
    bf16x8 qlo, qhi;
#pragma unroll
    for (int k = 0; k < 8; ++k) {
      h16x2 p = csp[k];
      float co = (float)p[0], si = (float)p[1];
      float v0 = (float)lo[k], v1 = (float)hi[k];
      qlo[k] = (bf16)(v0 * co - v1 * si);
      qhi[k] = (bf16)(v1 * co + v0 * si);
    }
    *(bf16x8*)&qr[base] = qlo;
    *(bf16x8*)&qr[base + 1024] = qhi;
  }
}

// ---------- launch ----------
extern "C" void kernel_launch(void* const* d_in, const int* in_sizes, int n_in,
                              void* d_out, int out_size, void* d_ws, size_t ws_size,
                              hipStream_t stream) {
  const float* x = (const float*)d_in[0];
  const float* Wi = (const float*)d_in[1];
  const float* bi = (const float*)d_in[2];
  const float* enc = (const float*)d_in[3];
  const float* encv = (const float*)d_in[4];
  const float* dec = (const float*)d_in[5];
  const float* Wo = (const float*)d_in[6];
  const float* bo = (const float*)d_in[7];
  float* out = (float*)d_out;

  const size_t NEED = 253000000;
  if (ws_size < NEED) return;

  char* w = (char*)d_ws;
  auto alloc = [&](size_t bytes) {
    char* p = w;
    w += (bytes + 255) & ~(size_t)255;
    return p;
  };
  bf16* encT = (bf16*)alloc((size_t)NHEADS * N_INT * 512 * 2);
  bf16* encvT = (bf16*)alloc((size_t)NHEADS * N_INT * 512 * 2);
  bf16* decT = (bf16*)alloc((size_t)512 * 16384 * 2);
  h16x2* cs = (h16x2*)alloc((size_t)T_SEQ * 1024 * 4);
  float* h = (float*)alloc((size_t)2048 * 512 * 4);
  bf16* hbf = (bf16*)alloc((size_t)2048 * 512 * 2);
  bf16* hT = (bf16*)alloc((size_t)2048 * 512 * 2);
  bf16* hsp = (bf16*)alloc((size_t)2 * NHEADS * T_SEQ * N_INT * 2);
  bf16* qr = (bf16*)alloc((size_t)2 * NHEADS * T_SEQ * N_INT * 2);
  bf16* S = (bf16*)alloc((size_t)2 * NHEADS * T_SEQ * T_SEQ * 2);
  bf16* ykv = (bf16*)alloc((size_t)2 * NHEADS * T_SEQ * 512 * 2);
  float* zbuf = (float*)alloc((size_t)2048 * 512 * 4);
  bf16* WoT = (bf16*)alloc((size_t)OUT_PAD * 512 * 2);
  bf16* xbf = S;
  bf16* WiT = S + 1048576;

  transpose_cvt<<<dim3(64, 16, 8), dim3(32, 8), 0, stream>>>(enc, encT, 512, N_INT);
  transpose_cvt<<<dim3(64, 16, 8), dim3(32, 8), 0, stream>>>(encv, encvT, 512, N_INT);
  transpose_cvt<<<dim3(16, 512, 1), dim3(32, 8), 0, stream>>>(dec, decT, 16384, 512);
  pad_trans<<<dim3(16, 12), dim3(32, 8), 0, stream>>>(Wi, WiT, IN_DIM, 512, IN_PAD);
  pad_trans<<<dim3(8, 16), dim3(32, 8), 0, stream>>>(Wo, WoT, 512, OUT_DIM, 512);
  cvt_pad_x<<<2048, 256, 0, stream>>>(x, xbf);
  rope_tables<<<1024, 256, 0, stream>>>(cs);
  g_in<<<64, 256, 0, stream>>>(xbf, WiT, bi, zbuf);
  ln0<<<2048, 256, 0, stream>>>(zbuf, h, hbf, hT);

  for (int L = 0; L < 3; ++L) {
    g_hspr<<<2048, 256, 0, stream>>>(hbf, encT, cs, hsp, qr);
    g_scores<<<1152, 256, 0, stream>>>(qr, S);
    g_pv<<<1024, 256, 0, stream>>>(S, hT, ykv);
    ln_rows<<<4096, 256, 0, stream>>>(ykv);
    g_gate<<<2048, 256, 0, stream>>>(ykv, encvT, hsp, qr);
    g_dec<<<512, 256, 0, stream>>>(qr, decT, S);
    psum_lnd<<<2048, 256, 0, stream>>>(S, h, hbf, hT);
  }
  g_out<<<32, 256, 0, stream>>>(hbf, WoT, bo, out);
}